// Round 9
// baseline (546.092 us; speedup 1.0000x reference)
//
#include <hip/hip_runtime.h>
#include <math.h>

typedef __bf16 bf16_t;
typedef __bf16 bf16x8 __attribute__((ext_vector_type(8)));
typedef float f32x4 __attribute__((ext_vector_type(4)));

#define GLOAD_LDS16(g, l)                                                      \
  __builtin_amdgcn_global_load_lds(                                            \
      (const __attribute__((address_space(1))) void*)(g),                      \
      (__attribute__((address_space(3))) void*)(l), 16, 0, 0)

// ---------------------------------------------------------------------------
// Prep: build bf16 operands.
// ---------------------------------------------------------------------------
__global__ __launch_bounds__(256) void prep_kernel(
    const float* __restrict__ enc, const float* __restrict__ dec,
    const float* __restrict__ ot, const float* __restrict__ W_enc,
    const float* __restrict__ W_ot, const float* __restrict__ W_dec,
    const float* __restrict__ W_out, bf16_t* __restrict__ Acat,
    bf16_t* __restrict__ Dec, bf16_t* __restrict__ WcatT,
    bf16_t* __restrict__ WdecT, bf16_t* __restrict__ WoutT) {
  int idx = blockIdx.x * 256 + threadIdx.x;
  const int N0 = 1600 * 1024, N1 = 400 * 512, N2 = 640 * 1024, N3 = 640 * 512,
            N4 = 1024 * 640;
  if (idx < N0) {
    int r = idx >> 10, c = idx & 1023;
    float v = (c < 512) ? enc[(r << 9) + c] : ot[(r << 9) + (c - 512)];
    Acat[idx] = (bf16_t)v;
    return;
  }
  idx -= N0;
  if (idx < N1) {
    Dec[idx] = (bf16_t)dec[idx];
    return;
  }
  idx -= N1;
  if (idx < N2) {
    int f = idx >> 10, k = idx & 1023;
    float v = (k < 512) ? W_enc[k * 640 + f] : W_ot[(k - 512) * 640 + f];
    WcatT[idx] = (bf16_t)v;
    return;
  }
  idx -= N2;
  if (idx < N3) {
    int f = idx >> 9, k = idx & 511;
    WdecT[idx] = (bf16_t)W_dec[k * 640 + f];
    return;
  }
  idx -= N3;
  if (idx < N4) {
    int v = idx / 640, f = idx - v * 640;
    WoutT[idx] = (bf16_t)W_out[f * 1024 + v];
    return;
  }
}

// ---------------------------------------------------------------------------
// Stage 1: out[M][640] = tanh(A[M][K] @ Bt[640][K]^T + bias1 (+ bias2))
// ---------------------------------------------------------------------------
__global__ __launch_bounds__(256) void gemm_tanh_kernel(
    const bf16_t* __restrict__ A, const bf16_t* __restrict__ Bt,
    const float* __restrict__ bias1, const float* __restrict__ bias2,
    float* __restrict__ out, int M, int K) {
  __shared__ bf16_t As[64 * 32];
  __shared__ bf16_t Bs[64 * 32];
  const int tid = threadIdx.x;
  const int wid = tid >> 6, lane = tid & 63;
  const int wm = wid >> 1, wn = wid & 1;
  const int r0 = blockIdx.y * 64, n0 = blockIdx.x * 64;

  const int ia = wid * 16 + (lane >> 2);
  const int sa = lane & 3;
  int ra = r0 + ia;
  if (ra > M - 1) ra = M - 1;
  const bf16_t* gA = A + (size_t)ra * K + sa * 8;
  const bf16_t* gB = Bt + (size_t)(n0 + ia) * K + sa * 8;
  bf16_t* lA = As + wid * 512;
  bf16_t* lB = Bs + wid * 512;

  f32x4 acc[2][2] = {};
  const int lr = lane & 15, kg = lane >> 4;
  const int steps = K >> 5;
  for (int ks = 0; ks < steps; ++ks) {
    GLOAD_LDS16(gA + ks * 32, lA);
    GLOAD_LDS16(gB + ks * 32, lB);
    __syncthreads();
    bf16x8 af[2], bfr[2];
#pragma unroll
    for (int a = 0; a < 2; ++a)
      af[a] = *(const bf16x8*)(As + (wm * 32 + a * 16 + lr) * 32 + kg * 8);
#pragma unroll
    for (int b = 0; b < 2; ++b)
      bfr[b] = *(const bf16x8*)(Bs + (wn * 32 + b * 16 + lr) * 32 + kg * 8);
#pragma unroll
    for (int a = 0; a < 2; ++a)
#pragma unroll
      for (int b = 0; b < 2; ++b)
        acc[a][b] =
            __builtin_amdgcn_mfma_f32_16x16x32_bf16(af[a], bfr[b], acc[a][b], 0, 0, 0);
    __syncthreads();
  }
#pragma unroll
  for (int a = 0; a < 2; ++a)
#pragma unroll
    for (int b = 0; b < 2; ++b) {
      int col = n0 + wn * 32 + b * 16 + lr;
      float bv = bias1[col] + (bias2 ? bias2[col] : 0.0f);
#pragma unroll
      for (int j = 0; j < 4; ++j) {
        int rg = r0 + wm * 32 + a * 16 + kg * 4 + j;
        if (rg < M) out[(size_t)rg * 640 + col] = tanhf(acc[a][b][j] + bv);
      }
    }
}

// ---------------------------------------------------------------------------
// Materialize joint A: Amat[80640][640] bf16 = tanh(fused+proj_dec) via the
// tanh addition identity. Pad rows [80000,80640) zeroed.
// ---------------------------------------------------------------------------
__global__ __launch_bounds__(256) void materialize_joint_kernel(
    const float* __restrict__ ta,   // [1600][640]
    const float* __restrict__ tb,   // [400][640]
    bf16_t* __restrict__ Amat) {    // [80640][640]
  const int idx = blockIdx.x * 256 + threadIdx.x;  // 0 .. 80640*80-1
  const int row = idx / 80;
  const int s = idx - row * 80;
  bf16x8 jv;
  if (row >= 80000) {
#pragma unroll
    for (int e = 0; e < 8; ++e) jv[e] = (bf16_t)0.0f;
    *(bf16x8*)(Amat + (size_t)row * 640 + s * 8) = jv;
    return;
  }
  const int frow = row / 50;          // b*T + t
  const int bidx = row / 10000;       // b
  const int u = row - frow * 50;      // u
  const float* taP = ta + (size_t)frow * 640 + s * 8;
  const float* tbP = tb + (size_t)(bidx * 50 + u) * 640 + s * 8;
#pragma unroll
  for (int h = 0; h < 2; ++h) {
    f32x4 xa = *(const f32x4*)(taP + h * 4);
    f32x4 xb = *(const f32x4*)(tbP + h * 4);
#pragma unroll
    for (int e = 0; e < 4; ++e) {
      float d = fmaxf(1.0f + xa[e] * xb[e], 1e-6f);
      jv[h * 4 + e] = (bf16_t)((xa[e] + xb[e]) * __builtin_amdgcn_rcpf(d));
    }
  }
  *(bf16x8*)(Amat + (size_t)row * 640 + s * 8) = jv;
}

// ---------------------------------------------------------------------------
// Stage 2: BARRIER-FREE joint GEMM (B-panel resident in LDS).
//  out[80000][1024] = Amat[80640][640] @ WoutT[1024][640]^T + b_out
//  Block: 256 thr / 4 waves; owns (panel p: 64 N-cols, chunk c: 1280 M-rows).
//  B-panel [64 cols][640 K] = 80 KB staged to LDS ONCE (swizzled ds_write),
//  then ZERO barriers: each wave streams its own 320 rows in 5 iters of
//  64 rows; A-frags read DIRECTLY global->VGPR (16 rows x 64 B = full
//  64-B-sector coalescing; 16x panel reuse via L1/L2); B-frags from the
//  resident panel; stores fire async between iters. Waves self-pipeline
//  (double-buffered frag regs, no inter-wave sync) -- removes the
//  vmcnt(0)-drain-before-barrier defect shared by all R2-R8 schedules.
//  B-swizzle: row stride 1280 B => bank(row)==0 mod 32; 16-B slot low-3
//  bits ^= (row&7) spreads 8 positions; 2-way residual = free (m136).
//  XCD map: wg=(orig&7)*126+(orig>>3), wg=(c,p) c-major => the 16 panels
//  of a chunk co-XCD => A-chunk (1.6 MB) L2-resident, fetched ~once.
// ---------------------------------------------------------------------------
__global__ __launch_bounds__(256, 2) void joint_gemm_kernel(
    const bf16_t* __restrict__ Amat,   // [80640][640]
    const bf16_t* __restrict__ WoutT,  // [1024][640]
    const float* __restrict__ b_out,   // [1024]
    float* __restrict__ out) {         // [80000][1024]
  __shared__ bf16_t Bs[64 * 640];  // 80 KB resident B-panel
  const int tid = threadIdx.x;
  const int w = tid >> 6, l = tid & 63;

  const int orig = blockIdx.x;  // grid 1008 = 63 chunks x 16 panels
  const int wg = (orig & 7) * 126 + (orig >> 3);
  const int p = wg & 15, c = wg >> 4;
  const int n0 = p * 64;
  const int r0c = c * 1280;

  // ---- one-time B-panel stage: thread (row=tid>>2, q=tid&3) loads 20
  //      16-B slots (stride 64 B), writes swizzled ----
  {
    const int row = tid >> 2, q = tid & 3;
    const bf16_t* gsrc = WoutT + (size_t)(n0 + row) * 640;
    bf16_t* ldst = Bs + row * 640;
    const int x = row & 7;
#pragma unroll
    for (int i = 0; i < 20; ++i) {
      const int slot = q + 4 * i;
      const int slotp = (slot & ~7) | ((slot & 7) ^ x);
      *(bf16x8*)(ldst + slotp * 8) = *(const bf16x8*)(gsrc + slot * 8);
    }
  }
  __syncthreads();  // the ONLY barrier in this kernel

  // ---- per-lane invariants ----
  const int lr = l & 15, kg = l >> 4;
  // B-frag: rr(nf) = nf*16+lr; byte = rr*1280 + (ks>>1)*128 + slotlo*16,
  //         slotlo = ((ks&1)*4 + kg) ^ (rr&7)
  int bbase[4], bxor[4];
#pragma unroll
  for (int nf = 0; nf < 4; ++nf) {
    const int rr = nf * 16 + lr;
    bbase[nf] = rr * 640;      // element offset (rr*1280 bytes)
    bxor[nf] = rr & 7;
  }
  float bv[4];
#pragma unroll
  for (int nf = 0; nf < 4; ++nf) bv[nf] = b_out[n0 + nf * 16 + lr];

#define LOADK(ks, AF, BF)                                                      \
  {                                                                            \
    _Pragma("unroll") for (int a = 0; a < 4; ++a) AF[a] =                      \
        *(const bf16x8*)(Ap + a * (16 * 640) + (ks) * 32);                     \
    _Pragma("unroll") for (int nf = 0; nf < 4; ++nf) BF[nf] =                  \
        *(const bf16x8*)(Bs + bbase[nf] + ((ks) >> 1) * 64 +                   \
                         ((((ks) & 1) * 4 + kg) ^ bxor[nf]) * 8);              \
  }
#define MFMA16(AF, BF)                                                         \
  {                                                                            \
    _Pragma("unroll") for (int a = 0; a < 4; ++a)                              \
        _Pragma("unroll") for (int nf = 0; nf < 4; ++nf) acc[a][nf] =          \
            __builtin_amdgcn_mfma_f32_16x16x32_bf16(AF[a], BF[nf],             \
                                                    acc[a][nf], 0, 0, 0);      \
  }

  // ---- 5 iterations of 64 rows per wave; no barriers ----
#pragma unroll 1
  for (int it = 0; it < 5; ++it) {
    const int r0i = r0c + w * 320 + it * 64;
    const bf16_t* Ap = Amat + (size_t)(r0i + lr) * 640 + kg * 8;

    f32x4 acc[4][4] = {};
    bf16x8 af0[4], bf0[4], af1[4], bf1[4];
    LOADK(0, af0, bf0);
#pragma unroll
    for (int ks = 0; ks < 20; ks += 2) {
      if (ks + 1 < 20) LOADK(ks + 1, af1, bf1);
      MFMA16(af0, bf0);
      if (ks + 2 < 20) LOADK(ks + 2, af0, bf0);
      MFMA16(af1, bf1);
    }

    // async epilogue (no sync; stores overlap next iter)
#pragma unroll
    for (int nf = 0; nf < 4; ++nf) {
      const int col = n0 + nf * 16 + lr;
#pragma unroll
      for (int a = 0; a < 4; ++a) {
        const int rg = r0i + a * 16 + kg * 4;
        float* op = out + (size_t)rg * 1024 + col;
        const f32x4 v = acc[a][nf];
#pragma unroll
        for (int j = 0; j < 4; ++j)
          if (rg + j < 80000) op[(size_t)j * 1024] = v[j] + bv[nf];
      }
    }
  }
#undef LOADK
#undef MFMA16
}

// ---------------------------------------------------------------------------
extern "C" void kernel_launch(void* const* d_in, const int* in_sizes, int n_in,
                              void* d_out, int out_size, void* d_ws,
                              size_t ws_size, hipStream_t stream) {
  const float* enc = (const float*)d_in[0];
  const float* dec = (const float*)d_in[1];
  const float* ot = (const float*)d_in[2];
  const float* W_enc = (const float*)d_in[3];
  const float* b_enc = (const float*)d_in[4];
  const float* W_ot = (const float*)d_in[5];
  const float* b_ot = (const float*)d_in[6];
  const float* W_dec = (const float*)d_in[7];
  const float* b_dec = (const float*)d_in[8];
  const float* W_out = (const float*)d_in[9];
  const float* b_out = (const float*)d_in[10];
  float* out = (float*)d_out;

  char* ws = (char*)d_ws;
  size_t off = 0;
  auto alloc = [&](size_t bytes) {
    void* p = ws + off;
    off += (bytes + 255) & ~(size_t)255;
    return p;
  };
  float* ta = (float*)alloc(1600 * 640 * 4);        // tanh(fused)
  float* tb = (float*)alloc(400 * 640 * 4);         // tanh(proj_dec)
  bf16_t* Acat = (bf16_t*)alloc(1600 * 1024 * 2);
  bf16_t* Dec = (bf16_t*)alloc(400 * 512 * 2);
  bf16_t* WcatT = (bf16_t*)alloc(640 * 1024 * 2);
  bf16_t* WdecT = (bf16_t*)alloc(640 * 512 * 2);
  bf16_t* WoutT = (bf16_t*)alloc(1024 * 640 * 2);
  bf16_t* Amat = (bf16_t*)alloc((size_t)80640 * 640 * 2);  // joint bf16

  prep_kernel<<<13600, 256, 0, stream>>>(enc, dec, ot, W_enc, W_ot, W_dec,
                                         W_out, Acat, Dec, WcatT, WdecT, WoutT);
  gemm_tanh_kernel<<<dim3(10, 25), 256, 0, stream>>>(Acat, WcatT, b_enc, b_ot,
                                                     ta, 1600, 1024);
  gemm_tanh_kernel<<<dim3(10, 7), 256, 0, stream>>>(Dec, WdecT, b_dec, nullptr,
                                                    tb, 400, 512);
  materialize_joint_kernel<<<25200, 256, 0, stream>>>(ta, tb, Amat);
  // joint: barrier-free, B-resident; 1008 = 63 chunks x 16 panels
  joint_gemm_kernel<<<1008, 256, 0, stream>>>(Amat, WoutT, b_out, out);
}

// Round 10
// 203.985 us; speedup vs baseline: 2.6771x; 2.6771x over previous
//
#include <hip/hip_runtime.h>
#include <math.h>

typedef __bf16 bf16_t;
typedef __bf16 bf16x8 __attribute__((ext_vector_type(8)));
typedef float f32x4 __attribute__((ext_vector_type(4)));
typedef int i32x4 __attribute__((ext_vector_type(4)));

#define SW_SCALE 0.03952847075f  /* 1/sqrt(640); shared by prep & epilogue */

#define GLOAD_LDS16(g, l)                                                      \
  __builtin_amdgcn_global_load_lds(                                            \
      (const __attribute__((address_space(1))) void*)(g),                      \
      (__attribute__((address_space(3))) void*)(l), 16, 0, 0)

// ---------------------------------------------------------------------------
// Prep: bf16 operands for stage 1 + i8 W_out for stage 2.
// ---------------------------------------------------------------------------
__global__ __launch_bounds__(256) void prep_kernel(
    const float* __restrict__ enc, const float* __restrict__ dec,
    const float* __restrict__ ot, const float* __restrict__ W_enc,
    const float* __restrict__ W_ot, const float* __restrict__ W_dec,
    const float* __restrict__ W_out, bf16_t* __restrict__ Acat,
    bf16_t* __restrict__ Dec, bf16_t* __restrict__ WcatT,
    bf16_t* __restrict__ WdecT, signed char* __restrict__ WoutT8) {
  int idx = blockIdx.x * 256 + threadIdx.x;
  const int N0 = 1600 * 1024, N1 = 400 * 512, N2 = 640 * 1024, N3 = 640 * 512,
            N4 = 1024 * 640;
  if (idx < N0) {
    int r = idx >> 10, c = idx & 1023;
    float v = (c < 512) ? enc[(r << 9) + c] : ot[(r << 9) + (c - 512)];
    Acat[idx] = (bf16_t)v;
    return;
  }
  idx -= N0;
  if (idx < N1) {
    Dec[idx] = (bf16_t)dec[idx];
    return;
  }
  idx -= N1;
  if (idx < N2) {
    int f = idx >> 10, k = idx & 1023;
    float v = (k < 512) ? W_enc[k * 640 + f] : W_ot[(k - 512) * 640 + f];
    WcatT[idx] = (bf16_t)v;
    return;
  }
  idx -= N2;
  if (idx < N3) {
    int f = idx >> 9, k = idx & 511;
    WdecT[idx] = (bf16_t)W_dec[k * 640 + f];
    return;
  }
  idx -= N3;
  if (idx < N4) {
    int v = idx / 640, f = idx - v * 640;
    float w = W_out[f * 1024 + v] * (127.0f / SW_SCALE);
    w = fminf(fmaxf(w, -127.0f), 127.0f);
    WoutT8[idx] = (signed char)__float2int_rn(w);
    return;
  }
}

// ---------------------------------------------------------------------------
// Stage 1: out[M][640] = tanh(A[M][K] @ Bt[640][K]^T + bias1 (+ bias2))
// ---------------------------------------------------------------------------
__global__ __launch_bounds__(256) void gemm_tanh_kernel(
    const bf16_t* __restrict__ A, const bf16_t* __restrict__ Bt,
    const float* __restrict__ bias1, const float* __restrict__ bias2,
    float* __restrict__ out, int M, int K) {
  __shared__ bf16_t As[64 * 32];
  __shared__ bf16_t Bs[64 * 32];
  const int tid = threadIdx.x;
  const int wid = tid >> 6, lane = tid & 63;
  const int wm = wid >> 1, wn = wid & 1;
  const int r0 = blockIdx.y * 64, n0 = blockIdx.x * 64;

  const int ia = wid * 16 + (lane >> 2);
  const int sa = lane & 3;
  int ra = r0 + ia;
  if (ra > M - 1) ra = M - 1;
  const bf16_t* gA = A + (size_t)ra * K + sa * 8;
  const bf16_t* gB = Bt + (size_t)(n0 + ia) * K + sa * 8;
  bf16_t* lA = As + wid * 512;
  bf16_t* lB = Bs + wid * 512;

  f32x4 acc[2][2] = {};
  const int lr = lane & 15, kg = lane >> 4;
  const int steps = K >> 5;
  for (int ks = 0; ks < steps; ++ks) {
    GLOAD_LDS16(gA + ks * 32, lA);
    GLOAD_LDS16(gB + ks * 32, lB);
    __syncthreads();
    bf16x8 af[2], bfr[2];
#pragma unroll
    for (int a = 0; a < 2; ++a)
      af[a] = *(const bf16x8*)(As + (wm * 32 + a * 16 + lr) * 32 + kg * 8);
#pragma unroll
    for (int b = 0; b < 2; ++b)
      bfr[b] = *(const bf16x8*)(Bs + (wn * 32 + b * 16 + lr) * 32 + kg * 8);
#pragma unroll
    for (int a = 0; a < 2; ++a)
#pragma unroll
      for (int b = 0; b < 2; ++b)
        acc[a][b] =
            __builtin_amdgcn_mfma_f32_16x16x32_bf16(af[a], bfr[b], acc[a][b], 0, 0, 0);
    __syncthreads();
  }
#pragma unroll
  for (int a = 0; a < 2; ++a)
#pragma unroll
    for (int b = 0; b < 2; ++b) {
      int col = n0 + wn * 32 + b * 16 + lr;
      float bv = bias1[col] + (bias2 ? bias2[col] : 0.0f);
#pragma unroll
      for (int j = 0; j < 4; ++j) {
        int rg = r0 + wm * 32 + a * 16 + kg * 4 + j;
        if (rg < M) out[(size_t)rg * 640 + col] = tanhf(acc[a][b][j] + bv);
      }
    }
}

// ---------------------------------------------------------------------------
// Stage 2: fused joint GEMM in i8 (R4 structure, halved bytes/FLOP-slots).
//  out[80000][1024] = q127(tanh-combined A)[80000][640] @ WoutT8^T * c + b_out
//  Tile 128x256, 512 thr, 8 waves (2Mx4N), wave tile 64x64. i8 MFMA
//  16x16x64 -> BK=64, 10 K-steps, 10 barriers total.
//  A: generated in-kernel via tanh addition identity, quantized to i8
//     (|t|<=1 exactly by identity), ds_write_b128 to swizzled slots.
//  B: pre-quantized WoutT8, gload_lds with pre-permuted source col.
//  Swizzle (R7-verified, conflicts=0): 64 B rows; slot^=((row>>1)&3) on
//  both write and read.  LDS 2x(8K A + 16K B) = 48 KB -> 2 blocks/CU.
//  Epilogue: i32 acc * SW_SCALE/127^2 + b_out, f32 store.
// ---------------------------------------------------------------------------
__global__ __launch_bounds__(512, 4) void joint_gemm_kernel(
    const float* __restrict__ ta,            // [1600][640]  tanh(fused)
    const float* __restrict__ tb,            // [400][640]   tanh(proj_dec)
    const signed char* __restrict__ WoutT8,  // [1024][640]  i8
    const float* __restrict__ b_out,         // [1024]
    float* __restrict__ out) {               // [80000][1024]
  __shared__ __align__(16) signed char L[2][24576];  // A [0,8K) B [8K,24K)
  const int tid = threadIdx.x;
  const int wid = tid >> 6, l = tid & 63;
  const int wm = wid >> 2, wn = wid & 3;
  const int r0 = blockIdx.y * 128;
  const int n0 = blockIdx.x * 256;

  // ---- A-gen assignment: thread -> (row i = tid>>2, slot s = tid&3) ----
  const int i = tid >> 2, s = tid & 3;
  const int r = r0 + i;
  const int frow = r / 50;
  const int bidx = r / 10000;
  const int u = r - frow * 50;
  const float* taP = ta + (size_t)frow * 640 + s * 16;
  const float* tbP = tb + (size_t)(bidx * 50 + u) * 640 + s * 16;
  // swizzled ds_write byte addr: row stride 64 B, slot ^= (row>>1)&3
  const int aw = i * 64 + ((s ^ ((i >> 1) & 3)) << 4);

  // ---- B staging: wave stages rows [wid*32, wid*32+32): 2 x gload_lds ----
  const int brow = wid * 32 + (l >> 2);
  const int sperm = ((l & 3) ^ ((l >> 3) & 3)) << 4;  // byte offset in row
  const signed char* gB0 = WoutT8 + (size_t)(n0 + brow) * 640 + sperm;
  const signed char* gB1 = gB0 + 16 * 640;
  const int dB0 = 8192 + wid * 2048;  // wave-uniform; HW adds lane*16B
  const int dB1 = dB0 + 1024;

  // ---- frag read byte offsets (row stride 64 B, swizzled slot) ----
  const int kg = l >> 4;
  int aoff[4], boff[4];
#pragma unroll
  for (int f = 0; f < 4; ++f) {
    const int ra = wm * 64 + f * 16 + (l & 15);
    aoff[f] = ra * 64 + ((kg ^ ((ra >> 1) & 3)) << 4);
    const int rb = wn * 64 + f * 16 + (l & 15);
    boff[f] = 8192 + rb * 64 + ((kg ^ ((rb >> 1) & 3)) << 4);
  }

  // A-gen: tanh addition identity -> q127 -> pack 16 i8 into i32x4
  auto genA = [&](int t, signed char* dst) {
    i32x4 pk;
#pragma unroll
    for (int c = 0; c < 4; ++c) {
      f32x4 xa = *(const f32x4*)(taP + t * 64 + c * 4);
      f32x4 xb = *(const f32x4*)(tbP + t * 64 + c * 4);
      int q[4];
#pragma unroll
      for (int e = 0; e < 4; ++e) {
        float d = fmaxf(1.0f + xa[e] * xb[e], 1e-6f);
        float tt = (xa[e] + xb[e]) * __builtin_amdgcn_rcpf(d);
        q[e] = __float2int_rn(tt * 127.0f);
      }
      pk[c] = (q[0] & 255) | ((q[1] & 255) << 8) | ((q[2] & 255) << 16) |
              (q[3] << 24);
    }
    *(i32x4*)(dst + aw) = pk;
  };

  i32x4 acc[4][4] = {};

  // ---- prologue: stage K-tile 0 into buf 0 ----
  GLOAD_LDS16(gB0, L[0] + dB0);
  GLOAD_LDS16(gB1, L[0] + dB1);
  genA(0, L[0]);
  __syncthreads();

#pragma unroll 1
  for (int t = 0; t < 10; ++t) {
    const int cur = t & 1, nxt = cur ^ 1;
    // -- issue next-tile stage first (flies during frag reads + MFMA) --
    if (t < 9) {
      const size_t ko = (size_t)(t + 1) * 64;
      GLOAD_LDS16(gB0 + ko, L[nxt] + dB0);
      GLOAD_LDS16(gB1 + ko, L[nxt] + dB1);
      genA(t + 1, L[nxt]);
    }
    // -- compute current tile --
    i32x4 af[4];
#pragma unroll
    for (int f = 0; f < 4; ++f) af[f] = *(const i32x4*)(L[cur] + aoff[f]);
#pragma unroll
    for (int bp = 0; bp < 2; ++bp) {
      i32x4 b0 = *(const i32x4*)(L[cur] + boff[2 * bp]);
      i32x4 b1 = *(const i32x4*)(L[cur] + boff[2 * bp + 1]);
#pragma unroll
      for (int a = 0; a < 4; ++a) {
        acc[a][2 * bp] = __builtin_amdgcn_mfma_i32_16x16x64_i8(
            af[a], b0, acc[a][2 * bp], 0, 0, 0);
        acc[a][2 * bp + 1] = __builtin_amdgcn_mfma_i32_16x16x64_i8(
            af[a], b1, acc[a][2 * bp + 1], 0, 0, 0);
      }
    }
    // -- single drain+barrier per K-tile (10 total) --
    __syncthreads();
  }

  // ---- epilogue: dequant + b_out, f32 store (C/D: col=l&15, row=kg*4+j) ----
  const float cfac = SW_SCALE / (127.0f * 127.0f);
#pragma unroll
  for (int b = 0; b < 4; ++b) {
    const int col = n0 + wn * 64 + b * 16 + (l & 15);
    const float bv = b_out[col];
#pragma unroll
    for (int a = 0; a < 4; ++a) {
      const int rg = r0 + wm * 64 + a * 16 + kg * 4;
      float* op = out + (size_t)rg * 1024 + col;
      const i32x4 v = acc[a][b];
#pragma unroll
      for (int j = 0; j < 4; ++j)
        op[(size_t)j * 1024] = (float)v[j] * cfac + bv;
    }
  }
}

// ---------------------------------------------------------------------------
extern "C" void kernel_launch(void* const* d_in, const int* in_sizes, int n_in,
                              void* d_out, int out_size, void* d_ws,
                              size_t ws_size, hipStream_t stream) {
  const float* enc = (const float*)d_in[0];
  const float* dec = (const float*)d_in[1];
  const float* ot = (const float*)d_in[2];
  const float* W_enc = (const float*)d_in[3];
  const float* b_enc = (const float*)d_in[4];
  const float* W_ot = (const float*)d_in[5];
  const float* b_ot = (const float*)d_in[6];
  const float* W_dec = (const float*)d_in[7];
  const float* b_dec = (const float*)d_in[8];
  const float* W_out = (const float*)d_in[9];
  const float* b_out = (const float*)d_in[10];
  float* out = (float*)d_out;

  char* ws = (char*)d_ws;
  size_t off = 0;
  auto alloc = [&](size_t bytes) {
    void* p = ws + off;
    off += (bytes + 255) & ~(size_t)255;
    return p;
  };
  float* ta = (float*)alloc(1600 * 640 * 4);        // tanh(fused)
  float* tb = (float*)alloc(400 * 640 * 4);         // tanh(proj_dec)
  bf16_t* Acat = (bf16_t*)alloc(1600 * 1024 * 2);
  bf16_t* Dec = (bf16_t*)alloc(400 * 512 * 2);
  bf16_t* WcatT = (bf16_t*)alloc(640 * 1024 * 2);
  bf16_t* WdecT = (bf16_t*)alloc(640 * 512 * 2);
  signed char* WoutT8 = (signed char*)alloc(1024 * 640);

  prep_kernel<<<13600, 256, 0, stream>>>(enc, dec, ot, W_enc, W_ot, W_dec,
                                         W_out, Acat, Dec, WcatT, WdecT,
                                         WoutT8);
  gemm_tanh_kernel<<<dim3(10, 25), 256, 0, stream>>>(Acat, WcatT, b_enc, b_ot,
                                                     ta, 1600, 1024);
  gemm_tanh_kernel<<<dim3(10, 7), 256, 0, stream>>>(Dec, WdecT, b_dec, nullptr,
                                                    tb, 400, 512);
  // joint: 128x256 tiles, 8 waves, i8 BK=64, 10 K-steps, 2 blocks/CU
  joint_gemm_kernel<<<dim3(4, 625), 512, 0, stream>>>(ta, tb, WoutT8, b_out,
                                                      out);
}

// Round 11
// 201.671 us; speedup vs baseline: 2.7078x; 1.0115x over previous
//
#include <hip/hip_runtime.h>
#include <math.h>

typedef __bf16 bf16_t;
typedef __bf16 bf16x8 __attribute__((ext_vector_type(8)));
typedef float f32x4 __attribute__((ext_vector_type(4)));
typedef int i32x4 __attribute__((ext_vector_type(4)));

#define SW_SCALE 0.03952847075f  /* 1/sqrt(640); shared by prep & epilogue */

#define GLOAD_LDS16(g, l)                                                      \
  __builtin_amdgcn_global_load_lds(                                            \
      (const __attribute__((address_space(1))) void*)(g),                      \
      (__attribute__((address_space(3))) void*)(l), 16, 0, 0)

// ---------------------------------------------------------------------------
// Prep: bf16 operands for stage 1 + i8 W_out for stage 2.
// ---------------------------------------------------------------------------
__global__ __launch_bounds__(256) void prep_kernel(
    const float* __restrict__ enc, const float* __restrict__ dec,
    const float* __restrict__ ot, const float* __restrict__ W_enc,
    const float* __restrict__ W_ot, const float* __restrict__ W_dec,
    const float* __restrict__ W_out, bf16_t* __restrict__ Acat,
    bf16_t* __restrict__ Dec, bf16_t* __restrict__ WcatT,
    bf16_t* __restrict__ WdecT, signed char* __restrict__ WoutT8) {
  int idx = blockIdx.x * 256 + threadIdx.x;
  const int N0 = 1600 * 1024, N1 = 400 * 512, N2 = 640 * 1024, N3 = 640 * 512,
            N4 = 1024 * 640;
  if (idx < N0) {
    int r = idx >> 10, c = idx & 1023;
    float v = (c < 512) ? enc[(r << 9) + c] : ot[(r << 9) + (c - 512)];
    Acat[idx] = (bf16_t)v;
    return;
  }
  idx -= N0;
  if (idx < N1) {
    Dec[idx] = (bf16_t)dec[idx];
    return;
  }
  idx -= N1;
  if (idx < N2) {
    int f = idx >> 10, k = idx & 1023;
    float v = (k < 512) ? W_enc[k * 640 + f] : W_ot[(k - 512) * 640 + f];
    WcatT[idx] = (bf16_t)v;
    return;
  }
  idx -= N2;
  if (idx < N3) {
    int f = idx >> 9, k = idx & 511;
    WdecT[idx] = (bf16_t)W_dec[k * 640 + f];
    return;
  }
  idx -= N3;
  if (idx < N4) {
    int v = idx / 640, f = idx - v * 640;
    float w = W_out[f * 1024 + v] * (127.0f / SW_SCALE);
    w = fminf(fmaxf(w, -127.0f), 127.0f);
    WoutT8[idx] = (signed char)__float2int_rn(w);
    return;
  }
}

// ---------------------------------------------------------------------------
// Stage 1: out[M][640] = tanh(A[M][K] @ Bt[640][K]^T + bias1 (+ bias2))
// ---------------------------------------------------------------------------
__global__ __launch_bounds__(256) void gemm_tanh_kernel(
    const bf16_t* __restrict__ A, const bf16_t* __restrict__ Bt,
    const float* __restrict__ bias1, const float* __restrict__ bias2,
    float* __restrict__ out, int M, int K) {
  __shared__ bf16_t As[64 * 32];
  __shared__ bf16_t Bs[64 * 32];
  const int tid = threadIdx.x;
  const int wid = tid >> 6, lane = tid & 63;
  const int wm = wid >> 1, wn = wid & 1;
  const int r0 = blockIdx.y * 64, n0 = blockIdx.x * 64;

  const int ia = wid * 16 + (lane >> 2);
  const int sa = lane & 3;
  int ra = r0 + ia;
  if (ra > M - 1) ra = M - 1;
  const bf16_t* gA = A + (size_t)ra * K + sa * 8;
  const bf16_t* gB = Bt + (size_t)(n0 + ia) * K + sa * 8;
  bf16_t* lA = As + wid * 512;
  bf16_t* lB = Bs + wid * 512;

  f32x4 acc[2][2] = {};
  const int lr = lane & 15, kg = lane >> 4;
  const int steps = K >> 5;
  for (int ks = 0; ks < steps; ++ks) {
    GLOAD_LDS16(gA + ks * 32, lA);
    GLOAD_LDS16(gB + ks * 32, lB);
    __syncthreads();
    bf16x8 af[2], bfr[2];
#pragma unroll
    for (int a = 0; a < 2; ++a)
      af[a] = *(const bf16x8*)(As + (wm * 32 + a * 16 + lr) * 32 + kg * 8);
#pragma unroll
    for (int b = 0; b < 2; ++b)
      bfr[b] = *(const bf16x8*)(Bs + (wn * 32 + b * 16 + lr) * 32 + kg * 8);
#pragma unroll
    for (int a = 0; a < 2; ++a)
#pragma unroll
      for (int b = 0; b < 2; ++b)
        acc[a][b] =
            __builtin_amdgcn_mfma_f32_16x16x32_bf16(af[a], bfr[b], acc[a][b], 0, 0, 0);
    __syncthreads();
  }
#pragma unroll
  for (int a = 0; a < 2; ++a)
#pragma unroll
    for (int b = 0; b < 2; ++b) {
      int col = n0 + wn * 32 + b * 16 + lr;
      float bv = bias1[col] + (bias2 ? bias2[col] : 0.0f);
#pragma unroll
      for (int j = 0; j < 4; ++j) {
        int rg = r0 + wm * 32 + a * 16 + kg * 4 + j;
        if (rg < M) out[(size_t)rg * 640 + col] = tanhf(acc[a][b][j] + bv);
      }
    }
}

// ---------------------------------------------------------------------------
// Stage 2: fused joint GEMM in i8 (R10 structure) + dwordx4 epilogue.
//  out[80000][1024] = q127(tanh-combined A)[80000][640] @ WoutT8^T * c + b_out
//  Tile 128x256, 512 thr, 8 waves (2Mx4N), wave tile 64x64. i8 MFMA
//  16x16x64 -> BK=64, 10 K-steps.
//  EPILOGUE (R11 change): per-wave LDS transpose of the 64x64 f32 tile in
//  16-row strips ([16][68]-padded f32, 2-way max bank alias = free), then
//  contiguous global_store_dwordx4 (16 lanes x 16 B = 256 B runs, 4 rows
//  per inst) -- the fill's 6.7 TB/s access shape, replacing the scalar
//  column-strided stores that pinned write BW at ~1.7 TB/s in R2-R10.
// ---------------------------------------------------------------------------
__global__ __launch_bounds__(512, 4) void joint_gemm_kernel(
    const float* __restrict__ ta,            // [1600][640]  tanh(fused)
    const float* __restrict__ tb,            // [400][640]   tanh(proj_dec)
    const signed char* __restrict__ WoutT8,  // [1024][640]  i8
    const float* __restrict__ b_out,         // [1024]
    float* __restrict__ out) {               // [80000][1024]
  __shared__ __align__(16) signed char L[2][24576];  // A [0,8K) B [8K,24K)
  const int tid = threadIdx.x;
  const int wid = tid >> 6, l = tid & 63;
  const int wm = wid >> 2, wn = wid & 3;
  const int r0 = blockIdx.y * 128;
  const int n0 = blockIdx.x * 256;

  // ---- A-gen assignment: thread -> (row i = tid>>2, slot s = tid&3) ----
  const int i = tid >> 2, s = tid & 3;
  const int r = r0 + i;
  const int frow = r / 50;
  const int bidx = r / 10000;
  const int u = r - frow * 50;
  const float* taP = ta + (size_t)frow * 640 + s * 16;
  const float* tbP = tb + (size_t)(bidx * 50 + u) * 640 + s * 16;
  // swizzled ds_write byte addr: row stride 64 B, slot ^= (row>>1)&3
  const int aw = i * 64 + ((s ^ ((i >> 1) & 3)) << 4);

  // ---- B staging: wave stages rows [wid*32, wid*32+32): 2 x gload_lds ----
  const int brow = wid * 32 + (l >> 2);
  const int sperm = ((l & 3) ^ ((l >> 3) & 3)) << 4;  // byte offset in row
  const signed char* gB0 = WoutT8 + (size_t)(n0 + brow) * 640 + sperm;
  const signed char* gB1 = gB0 + 16 * 640;
  const int dB0 = 8192 + wid * 2048;  // wave-uniform; HW adds lane*16B
  const int dB1 = dB0 + 1024;

  // ---- frag read byte offsets (row stride 64 B, swizzled slot) ----
  const int kg = l >> 4;
  int aoff[4], boff[4];
#pragma unroll
  for (int f = 0; f < 4; ++f) {
    const int ra = wm * 64 + f * 16 + (l & 15);
    aoff[f] = ra * 64 + ((kg ^ ((ra >> 1) & 3)) << 4);
    const int rb = wn * 64 + f * 16 + (l & 15);
    boff[f] = 8192 + rb * 64 + ((kg ^ ((rb >> 1) & 3)) << 4);
  }

  // A-gen: tanh addition identity -> q127 -> pack 16 i8 into i32x4
  auto genA = [&](int t, signed char* dst) {
    i32x4 pk;
#pragma unroll
    for (int c = 0; c < 4; ++c) {
      f32x4 xa = *(const f32x4*)(taP + t * 64 + c * 4);
      f32x4 xb = *(const f32x4*)(tbP + t * 64 + c * 4);
      int q[4];
#pragma unroll
      for (int e = 0; e < 4; ++e) {
        float d = fmaxf(1.0f + xa[e] * xb[e], 1e-6f);
        float tt = (xa[e] + xb[e]) * __builtin_amdgcn_rcpf(d);
        q[e] = __float2int_rn(tt * 127.0f);
      }
      pk[c] = (q[0] & 255) | ((q[1] & 255) << 8) | ((q[2] & 255) << 16) |
              (q[3] << 24);
    }
    *(i32x4*)(dst + aw) = pk;
  };

  i32x4 acc[4][4] = {};

  // ---- prologue: stage K-tile 0 into buf 0 ----
  GLOAD_LDS16(gB0, L[0] + dB0);
  GLOAD_LDS16(gB1, L[0] + dB1);
  genA(0, L[0]);
  __syncthreads();

#pragma unroll 1
  for (int t = 0; t < 10; ++t) {
    const int cur = t & 1, nxt = cur ^ 1;
    // -- issue next-tile stage first (flies during frag reads + MFMA) --
    if (t < 9) {
      const size_t ko = (size_t)(t + 1) * 64;
      GLOAD_LDS16(gB0 + ko, L[nxt] + dB0);
      GLOAD_LDS16(gB1 + ko, L[nxt] + dB1);
      genA(t + 1, L[nxt]);
    }
    // -- compute current tile --
    i32x4 af[4];
#pragma unroll
    for (int f = 0; f < 4; ++f) af[f] = *(const i32x4*)(L[cur] + aoff[f]);
#pragma unroll
    for (int bp = 0; bp < 2; ++bp) {
      i32x4 b0 = *(const i32x4*)(L[cur] + boff[2 * bp]);
      i32x4 b1 = *(const i32x4*)(L[cur] + boff[2 * bp + 1]);
#pragma unroll
      for (int a = 0; a < 4; ++a) {
        acc[a][2 * bp] = __builtin_amdgcn_mfma_i32_16x16x64_i8(
            af[a], b0, acc[a][2 * bp], 0, 0, 0);
        acc[a][2 * bp + 1] = __builtin_amdgcn_mfma_i32_16x16x64_i8(
            af[a], b1, acc[a][2 * bp + 1], 0, 0, 0);
      }
    }
    // -- single drain+barrier per K-tile (10 total) --
    __syncthreads();
  }

  // ---- R11 epilogue: dequant + bias, LDS transpose, dwordx4 stores ----
  __syncthreads();  // all waves done reading K-loop LDS; safe to repurpose
  const float cfac = SW_SCALE / (127.0f * 127.0f);
  const int lr15 = l & 15;
  float bvl[4];
#pragma unroll
  for (int b = 0; b < 4; ++b) bvl[b] = b_out[n0 + wn * 64 + b * 16 + lr15];

  // per-wave strip buffer: [16 rows][68 floats] (272 B row = 16-B aligned;
  // bank = 4*(row+col4)/... -> 2-way max alias on both write and b128 read)
  float* ep = (float*)(void*)L + (size_t)wid * (16 * 68);
  const int rowr = l >> 4;       // read: row-in-quad
  const int col4 = lr15 * 4;     // read: 4-float col group

#pragma unroll
  for (int a = 0; a < 4; ++a) {
    // write phase: 16 scalar ds_writes (col-major frags -> row-major strip)
#pragma unroll
    for (int b = 0; b < 4; ++b) {
      const i32x4 v = acc[a][b];
#pragma unroll
      for (int j = 0; j < 4; ++j)
        ep[(kg * 4 + j) * 68 + b * 16 + lr15] = (float)v[j] * cfac + bvl[b];
    }
    asm volatile("s_waitcnt lgkmcnt(0)" ::: "memory");
    // read+store phase: 4 x (ds_read_b128 + global_store_dwordx4)
#pragma unroll
    for (int it = 0; it < 4; ++it) {
      const int row = it * 4 + rowr;
      f32x4 v = *(const f32x4*)(ep + row * 68 + col4);
      const int rg = r0 + wm * 64 + a * 16 + row;
      *(f32x4*)(out + (size_t)rg * 1024 + n0 + wn * 64 + col4) = v;
    }
  }
}

// ---------------------------------------------------------------------------
extern "C" void kernel_launch(void* const* d_in, const int* in_sizes, int n_in,
                              void* d_out, int out_size, void* d_ws,
                              size_t ws_size, hipStream_t stream) {
  const float* enc = (const float*)d_in[0];
  const float* dec = (const float*)d_in[1];
  const float* ot = (const float*)d_in[2];
  const float* W_enc = (const float*)d_in[3];
  const float* b_enc = (const float*)d_in[4];
  const float* W_ot = (const float*)d_in[5];
  const float* b_ot = (const float*)d_in[6];
  const float* W_dec = (const float*)d_in[7];
  const float* b_dec = (const float*)d_in[8];
  const float* W_out = (const float*)d_in[9];
  const float* b_out = (const float*)d_in[10];
  float* out = (float*)d_out;

  char* ws = (char*)d_ws;
  size_t off = 0;
  auto alloc = [&](size_t bytes) {
    void* p = ws + off;
    off += (bytes + 255) & ~(size_t)255;
    return p;
  };
  float* ta = (float*)alloc(1600 * 640 * 4);        // tanh(fused)
  float* tb = (float*)alloc(400 * 640 * 4);         // tanh(proj_dec)
  bf16_t* Acat = (bf16_t*)alloc(1600 * 1024 * 2);
  bf16_t* Dec = (bf16_t*)alloc(400 * 512 * 2);
  bf16_t* WcatT = (bf16_t*)alloc(640 * 1024 * 2);
  bf16_t* WdecT = (bf16_t*)alloc(640 * 512 * 2);
  signed char* WoutT8 = (signed char*)alloc(1024 * 640);

  prep_kernel<<<13600, 256, 0, stream>>>(enc, dec, ot, W_enc, W_ot, W_dec,
                                         W_out, Acat, Dec, WcatT, WdecT,
                                         WoutT8);
  gemm_tanh_kernel<<<dim3(10, 25), 256, 0, stream>>>(Acat, WcatT, b_enc, b_ot,
                                                     ta, 1600, 1024);
  gemm_tanh_kernel<<<dim3(10, 7), 256, 0, stream>>>(Dec, WdecT, b_dec, nullptr,
                                                    tb, 400, 512);
  // joint: 128x256 tiles, 8 waves, i8 BK=64, dwordx4 epilogue
  joint_gemm_kernel<<<dim3(4, 625), 512, 0, stream>>>(ta, tb, WoutT8, b_out,
                                                      out);
}

// Round 12
// 191.188 us; speedup vs baseline: 2.8563x; 1.0548x over previous
//
#include <hip/hip_runtime.h>
#include <math.h>

typedef __bf16 bf16_t;
typedef __bf16 bf16x8 __attribute__((ext_vector_type(8)));
typedef float f32x4 __attribute__((ext_vector_type(4)));
typedef int i32x4 __attribute__((ext_vector_type(4)));

#define SW_SCALE 0.03952847075f  /* 1/sqrt(640); shared by prep & epilogue */

#define GLOAD_LDS16(g, l)                                                      \
  __builtin_amdgcn_global_load_lds(                                            \
      (const __attribute__((address_space(1))) void*)(g),                      \
      (__attribute__((address_space(3))) void*)(l), 16, 0, 0)

// ---------------------------------------------------------------------------
// Prep (R12): one kernel, job-per-block.
//  blocks [0,900):    vectorized elementwise -> Acat [1600][1024], Dec [400][512]
//  blocks [900,1540):  LDS-tiled transpose -> WcatT [640][1024]
//  blocks [1540,1860): LDS-tiled transpose -> WdecT [640][512]
//  blocks [1860,2500): LDS-tiled transpose+quant -> WoutT8 [1024][640] i8
//  All global reads AND writes coalesced (32x32 f32 tile via LDS [32][33]).
// ---------------------------------------------------------------------------
__global__ __launch_bounds__(256) void prep_kernel(
    const float* __restrict__ enc, const float* __restrict__ dec,
    const float* __restrict__ ot, const float* __restrict__ W_enc,
    const float* __restrict__ W_ot, const float* __restrict__ W_dec,
    const float* __restrict__ W_out, bf16_t* __restrict__ Acat,
    bf16_t* __restrict__ Dec, bf16_t* __restrict__ WcatT,
    bf16_t* __restrict__ WdecT, signed char* __restrict__ WoutT8) {
  __shared__ float T[32][33];
  const int tid = threadIdx.x;
  const int b = blockIdx.x;

  if (b < 900) {  // elementwise bf16x8 copies
    const int idx8 = (b * 256 + tid) * 8;
    const int N0 = 1600 * 1024;
    if (idx8 < N0) {
      const int r = idx8 >> 10, c = idx8 & 1023;
      const float* src = (c < 512) ? enc + (r << 9) + c : ot + (r << 9) + c - 512;
      f32x4 v0 = *(const f32x4*)src;
      f32x4 v1 = *(const f32x4*)(src + 4);
      bf16x8 o;
#pragma unroll
      for (int e = 0; e < 4; ++e) {
        o[e] = (bf16_t)v0[e];
        o[e + 4] = (bf16_t)v1[e];
      }
      *(bf16x8*)(Acat + idx8) = o;
    } else {
      const int j = idx8 - N0;
      if (j < 400 * 512) {
        f32x4 v0 = *(const f32x4*)(dec + j);
        f32x4 v1 = *(const f32x4*)(dec + j + 4);
        bf16x8 o;
#pragma unroll
        for (int e = 0; e < 4; ++e) {
          o[e] = (bf16_t)v0[e];
          o[e + 4] = (bf16_t)v1[e];
        }
        *(bf16x8*)(Dec + j) = o;
      }
    }
    return;
  }

  const int tx = tid & 31, ty = tid >> 5;  // 32 x 8, 4 rows each
  if (b < 1540) {  // WcatT: src rows k (W_enc/W_ot [512][640]), dest [f][k]
    const int b2 = b - 900;
    const int kt = b2 / 20, ft = b2 - kt * 20;
    const int k0 = kt * 32, f0 = ft * 32;
#pragma unroll
    for (int j = 0; j < 4; ++j) {
      const int kk = k0 + ty + j * 8;
      T[ty + j * 8][tx] = (kk < 512) ? W_enc[kk * 640 + f0 + tx]
                                     : W_ot[(kk - 512) * 640 + f0 + tx];
    }
    __syncthreads();
#pragma unroll
    for (int j = 0; j < 4; ++j) {
      const int ff = f0 + ty + j * 8;
      WcatT[ff * 1024 + k0 + tx] = (bf16_t)T[tx][ty + j * 8];
    }
    return;
  }
  if (b < 1860) {  // WdecT: src W_dec [512][640], dest [f][k]
    const int b2 = b - 1540;
    const int kt = b2 / 20, ft = b2 - kt * 20;
    const int k0 = kt * 32, f0 = ft * 32;
#pragma unroll
    for (int j = 0; j < 4; ++j)
      T[ty + j * 8][tx] = W_dec[(k0 + ty + j * 8) * 640 + f0 + tx];
    __syncthreads();
#pragma unroll
    for (int j = 0; j < 4; ++j) {
      const int ff = f0 + ty + j * 8;
      WdecT[ff * 512 + k0 + tx] = (bf16_t)T[tx][ty + j * 8];
    }
    return;
  }
  {  // WoutT8: src W_out [640][1024], dest [v][f] i8 quant
    const int b2 = b - 1860;
    const int vt = b2 / 20, ft = b2 - vt * 20;
    const int v0 = vt * 32, f0 = ft * 32;
#pragma unroll
    for (int j = 0; j < 4; ++j)
      T[ty + j * 8][tx] = W_out[(f0 + ty + j * 8) * 1024 + v0 + tx];
    __syncthreads();
#pragma unroll
    for (int j = 0; j < 4; ++j) {
      const int vv = v0 + ty + j * 8;
      float w = T[tx][ty + j * 8] * (127.0f / SW_SCALE);
      w = fminf(fmaxf(w, -127.0f), 127.0f);
      WoutT8[vv * 640 + f0 + tx] = (signed char)__float2int_rn(w);
    }
  }
}

// ---------------------------------------------------------------------------
// Stage 1: out[M][640] = tanh(A[M][K] @ Bt[640][K]^T + bias1 (+ bias2))
// ---------------------------------------------------------------------------
__global__ __launch_bounds__(256) void gemm_tanh_kernel(
    const bf16_t* __restrict__ A, const bf16_t* __restrict__ Bt,
    const float* __restrict__ bias1, const float* __restrict__ bias2,
    float* __restrict__ out, int M, int K) {
  __shared__ bf16_t As[64 * 32];
  __shared__ bf16_t Bs[64 * 32];
  const int tid = threadIdx.x;
  const int wid = tid >> 6, lane = tid & 63;
  const int wm = wid >> 1, wn = wid & 1;
  const int r0 = blockIdx.y * 64, n0 = blockIdx.x * 64;

  const int ia = wid * 16 + (lane >> 2);
  const int sa = lane & 3;
  int ra = r0 + ia;
  if (ra > M - 1) ra = M - 1;
  const bf16_t* gA = A + (size_t)ra * K + sa * 8;
  const bf16_t* gB = Bt + (size_t)(n0 + ia) * K + sa * 8;
  bf16_t* lA = As + wid * 512;
  bf16_t* lB = Bs + wid * 512;

  f32x4 acc[2][2] = {};
  const int lr = lane & 15, kg = lane >> 4;
  const int steps = K >> 5;
  for (int ks = 0; ks < steps; ++ks) {
    GLOAD_LDS16(gA + ks * 32, lA);
    GLOAD_LDS16(gB + ks * 32, lB);
    __syncthreads();
    bf16x8 af[2], bfr[2];
#pragma unroll
    for (int a = 0; a < 2; ++a)
      af[a] = *(const bf16x8*)(As + (wm * 32 + a * 16 + lr) * 32 + kg * 8);
#pragma unroll
    for (int b = 0; b < 2; ++b)
      bfr[b] = *(const bf16x8*)(Bs + (wn * 32 + b * 16 + lr) * 32 + kg * 8);
#pragma unroll
    for (int a = 0; a < 2; ++a)
#pragma unroll
      for (int b = 0; b < 2; ++b)
        acc[a][b] =
            __builtin_amdgcn_mfma_f32_16x16x32_bf16(af[a], bfr[b], acc[a][b], 0, 0, 0);
    __syncthreads();
  }
#pragma unroll
  for (int a = 0; a < 2; ++a)
#pragma unroll
    for (int b = 0; b < 2; ++b) {
      int col = n0 + wn * 32 + b * 16 + lr;
      float bv = bias1[col] + (bias2 ? bias2[col] : 0.0f);
#pragma unroll
      for (int j = 0; j < 4; ++j) {
        int rg = r0 + wm * 32 + a * 16 + kg * 4 + j;
        if (rg < M) out[(size_t)rg * 640 + col] = tanhf(acc[a][b][j] + bv);
      }
    }
}

// ---------------------------------------------------------------------------
// Stage 2: fused joint GEMM in i8 (R10/R11 structure) + NONTEMPORAL stores.
//  out = q127(tanh-combined A) @ WoutT8^T * c + b_out.  Tile 128x256,
//  512 thr, 8 waves, i8 MFMA 16x16x64, BK=64, 10 K-steps.
//  R12 change: epilogue global stores are NONTEMPORAL (output is written
//  once, never re-read -> bypass L2 allocate churn; WRITE excess bytes
//  observed in R7-R9 suggests write-path churn pinned stores ~1.8 TB/s).
// ---------------------------------------------------------------------------
__global__ __launch_bounds__(512, 4) void joint_gemm_kernel(
    const float* __restrict__ ta,            // [1600][640]  tanh(fused)
    const float* __restrict__ tb,            // [400][640]   tanh(proj_dec)
    const signed char* __restrict__ WoutT8,  // [1024][640]  i8
    const float* __restrict__ b_out,         // [1024]
    float* __restrict__ out) {               // [80000][1024]
  __shared__ __align__(16) signed char L[2][24576];  // A [0,8K) B [8K,24K)
  const int tid = threadIdx.x;
  const int wid = tid >> 6, l = tid & 63;
  const int wm = wid >> 2, wn = wid & 3;
  const int r0 = blockIdx.y * 128;
  const int n0 = blockIdx.x * 256;

  // ---- A-gen assignment: thread -> (row i = tid>>2, slot s = tid&3) ----
  const int i = tid >> 2, s = tid & 3;
  const int r = r0 + i;
  const int frow = r / 50;
  const int bidx = r / 10000;
  const int u = r - frow * 50;
  const float* taP = ta + (size_t)frow * 640 + s * 16;
  const float* tbP = tb + (size_t)(bidx * 50 + u) * 640 + s * 16;
  // swizzled ds_write byte addr: row stride 64 B, slot ^= (row>>1)&3
  const int aw = i * 64 + ((s ^ ((i >> 1) & 3)) << 4);

  // ---- B staging: wave stages rows [wid*32, wid*32+32): 2 x gload_lds ----
  const int brow = wid * 32 + (l >> 2);
  const int sperm = ((l & 3) ^ ((l >> 3) & 3)) << 4;  // byte offset in row
  const signed char* gB0 = WoutT8 + (size_t)(n0 + brow) * 640 + sperm;
  const signed char* gB1 = gB0 + 16 * 640;
  const int dB0 = 8192 + wid * 2048;  // wave-uniform; HW adds lane*16B
  const int dB1 = dB0 + 1024;

  // ---- frag read byte offsets (row stride 64 B, swizzled slot) ----
  const int kg = l >> 4;
  int aoff[4], boff[4];
#pragma unroll
  for (int f = 0; f < 4; ++f) {
    const int ra = wm * 64 + f * 16 + (l & 15);
    aoff[f] = ra * 64 + ((kg ^ ((ra >> 1) & 3)) << 4);
    const int rb = wn * 64 + f * 16 + (l & 15);
    boff[f] = 8192 + rb * 64 + ((kg ^ ((rb >> 1) & 3)) << 4);
  }

  // A-gen: tanh addition identity -> q127 -> pack 16 i8 into i32x4
  auto genA = [&](int t, signed char* dst) {
    i32x4 pk;
#pragma unroll
    for (int c = 0; c < 4; ++c) {
      f32x4 xa = *(const f32x4*)(taP + t * 64 + c * 4);
      f32x4 xb = *(const f32x4*)(tbP + t * 64 + c * 4);
      int q[4];
#pragma unroll
      for (int e = 0; e < 4; ++e) {
        float d = fmaxf(1.0f + xa[e] * xb[e], 1e-6f);
        float tt = (xa[e] + xb[e]) * __builtin_amdgcn_rcpf(d);
        q[e] = __float2int_rn(tt * 127.0f);
      }
      pk[c] = (q[0] & 255) | ((q[1] & 255) << 8) | ((q[2] & 255) << 16) |
              (q[3] << 24);
    }
    *(i32x4*)(dst + aw) = pk;
  };

  i32x4 acc[4][4] = {};

  // ---- prologue: stage K-tile 0 into buf 0 ----
  GLOAD_LDS16(gB0, L[0] + dB0);
  GLOAD_LDS16(gB1, L[0] + dB1);
  genA(0, L[0]);
  __syncthreads();

#pragma unroll 1
  for (int t = 0; t < 10; ++t) {
    const int cur = t & 1, nxt = cur ^ 1;
    // -- issue next-tile stage first (flies during frag reads + MFMA) --
    if (t < 9) {
      const size_t ko = (size_t)(t + 1) * 64;
      GLOAD_LDS16(gB0 + ko, L[nxt] + dB0);
      GLOAD_LDS16(gB1 + ko, L[nxt] + dB1);
      genA(t + 1, L[nxt]);
    }
    // -- compute current tile --
    i32x4 af[4];
#pragma unroll
    for (int f = 0; f < 4; ++f) af[f] = *(const i32x4*)(L[cur] + aoff[f]);
#pragma unroll
    for (int bp = 0; bp < 2; ++bp) {
      i32x4 b0 = *(const i32x4*)(L[cur] + boff[2 * bp]);
      i32x4 b1 = *(const i32x4*)(L[cur] + boff[2 * bp + 1]);
#pragma unroll
      for (int a = 0; a < 4; ++a) {
        acc[a][2 * bp] = __builtin_amdgcn_mfma_i32_16x16x64_i8(
            af[a], b0, acc[a][2 * bp], 0, 0, 0);
        acc[a][2 * bp + 1] = __builtin_amdgcn_mfma_i32_16x16x64_i8(
            af[a], b1, acc[a][2 * bp + 1], 0, 0, 0);
      }
    }
    // -- single drain+barrier per K-tile (10 total) --
    __syncthreads();
  }

  // ---- epilogue: dequant+bias, LDS transpose, NONTEMPORAL dwordx4 stores --
  __syncthreads();  // all waves done reading K-loop LDS; safe to repurpose
  const float cfac = SW_SCALE / (127.0f * 127.0f);
  const int lr15 = l & 15;
  float bvl[4];
#pragma unroll
  for (int b = 0; b < 4; ++b) bvl[b] = b_out[n0 + wn * 64 + b * 16 + lr15];

  // per-wave strip buffer: [16 rows][68 floats]
  float* ep = (float*)(void*)L + (size_t)wid * (16 * 68);
  const int rowr = l >> 4;
  const int col4 = lr15 * 4;

#pragma unroll
  for (int a = 0; a < 4; ++a) {
#pragma unroll
    for (int b = 0; b < 4; ++b) {
      const i32x4 v = acc[a][b];
#pragma unroll
      for (int j = 0; j < 4; ++j)
        ep[(kg * 4 + j) * 68 + b * 16 + lr15] = (float)v[j] * cfac + bvl[b];
    }
    asm volatile("s_waitcnt lgkmcnt(0)" ::: "memory");
#pragma unroll
    for (int it = 0; it < 4; ++it) {
      const int row = it * 4 + rowr;
      f32x4 v = *(const f32x4*)(ep + row * 68 + col4);
      const int rg = r0 + wm * 64 + a * 16 + row;
      __builtin_nontemporal_store(
          v, (f32x4*)(out + (size_t)rg * 1024 + n0 + wn * 64 + col4));
    }
  }
}

// ---------------------------------------------------------------------------
extern "C" void kernel_launch(void* const* d_in, const int* in_sizes, int n_in,
                              void* d_out, int out_size, void* d_ws,
                              size_t ws_size, hipStream_t stream) {
  const float* enc = (const float*)d_in[0];
  const float* dec = (const float*)d_in[1];
  const float* ot = (const float*)d_in[2];
  const float* W_enc = (const float*)d_in[3];
  const float* b_enc = (const float*)d_in[4];
  const float* W_ot = (const float*)d_in[5];
  const float* b_ot = (const float*)d_in[6];
  const float* W_dec = (const float*)d_in[7];
  const float* b_dec = (const float*)d_in[8];
  const float* W_out = (const float*)d_in[9];
  const float* b_out = (const float*)d_in[10];
  float* out = (float*)d_out;

  char* ws = (char*)d_ws;
  size_t off = 0;
  auto alloc = [&](size_t bytes) {
    void* p = ws + off;
    off += (bytes + 255) & ~(size_t)255;
    return p;
  };
  float* ta = (float*)alloc(1600 * 640 * 4);        // tanh(fused)
  float* tb = (float*)alloc(400 * 640 * 4);         // tanh(proj_dec)
  bf16_t* Acat = (bf16_t*)alloc(1600 * 1024 * 2);
  bf16_t* Dec = (bf16_t*)alloc(400 * 512 * 2);
  bf16_t* WcatT = (bf16_t*)alloc(640 * 1024 * 2);
  bf16_t* WdecT = (bf16_t*)alloc(640 * 512 * 2);
  signed char* WoutT8 = (signed char*)alloc(1024 * 640);

  // prep: 900 elementwise + 640 + 320 + 640 transpose-tile blocks
  prep_kernel<<<2500, 256, 0, stream>>>(enc, dec, ot, W_enc, W_ot, W_dec,
                                        W_out, Acat, Dec, WcatT, WdecT, WoutT8);
  gemm_tanh_kernel<<<dim3(10, 25), 256, 0, stream>>>(Acat, WcatT, b_enc, b_ot,
                                                     ta, 1600, 1024);
  gemm_tanh_kernel<<<dim3(10, 7), 256, 0, stream>>>(Dec, WdecT, b_dec, nullptr,
                                                    tb, 400, 512);
  // joint: 128x256 tiles, 8 waves, i8 BK=64, nontemporal epilogue
  joint_gemm_kernel<<<dim3(4, 625), 512, 0, stream>>>(ta, tb, WoutT8, b_out,
                                                      out);
}

// Round 13
// 191.057 us; speedup vs baseline: 2.8583x; 1.0007x over previous
//
#include <hip/hip_runtime.h>
#include <math.h>

typedef __bf16 bf16_t;
typedef __bf16 bf16x8 __attribute__((ext_vector_type(8)));
typedef float f32x4 __attribute__((ext_vector_type(4)));
typedef int i32x4 __attribute__((ext_vector_type(4)));

#define SW_SCALE 0.03952847075f /* 1/sqrt(640) */

#define GLOAD_LDS16(g, l)                                                      \
  __builtin_amdgcn_global_load_lds(                                            \
      (const __attribute__((address_space(1))) void*)(g),                      \
      (__attribute__((address_space(3))) void*)(l), 16, 0, 0)

// ---------------------------------------------------------------------------
// Prep. WoutT8 stores K-PERMUTED columns: within each 64-f block,
// phys f = 16c+4s+j is stored at f' = 16s+4c+j. The joint kernel's A-path
// generates the same k_lds order, so MFMA sums match bit-exactly (i32).
// ---------------------------------------------------------------------------
__global__ __launch_bounds__(256) void prep_kernel(
    const float* __restrict__ enc, const float* __restrict__ dec,
    const float* __restrict__ ot, const float* __restrict__ W_enc,
    const float* __restrict__ W_ot, const float* __restrict__ W_dec,
    const float* __restrict__ W_out, bf16_t* __restrict__ Acat,
    bf16_t* __restrict__ Dec, bf16_t* __restrict__ WcatT,
    bf16_t* __restrict__ WdecT, signed char* __restrict__ WoutT8) {
  __shared__ float T[64][33];
  const int tid = threadIdx.x;
  const int b = blockIdx.x;

  if (b < 900) {  // elementwise bf16x8 copies
    const int idx8 = (b * 256 + tid) * 8;
    const int N0 = 1600 * 1024;
    if (idx8 < N0) {
      const int r = idx8 >> 10, c = idx8 & 1023;
      const float* src = (c < 512) ? enc + (r << 9) + c : ot + (r << 9) + c - 512;
      f32x4 v0 = *(const f32x4*)src;
      f32x4 v1 = *(const f32x4*)(src + 4);
      bf16x8 o;
#pragma unroll
      for (int e = 0; e < 4; ++e) {
        o[e] = (bf16_t)v0[e];
        o[e + 4] = (bf16_t)v1[e];
      }
      *(bf16x8*)(Acat + idx8) = o;
    } else {
      const int j = idx8 - N0;
      if (j < 400 * 512) {
        f32x4 v0 = *(const f32x4*)(dec + j);
        f32x4 v1 = *(const f32x4*)(dec + j + 4);
        bf16x8 o;
#pragma unroll
        for (int e = 0; e < 4; ++e) {
          o[e] = (bf16_t)v0[e];
          o[e + 4] = (bf16_t)v1[e];
        }
        *(bf16x8*)(Dec + j) = o;
      }
    }
    return;
  }

  const int tx = tid & 31, ty = tid >> 5;
  if (b < 1540) {  // WcatT [f][k] <- [k][f]
    const int b2 = b - 900;
    const int kt = b2 / 20, ft = b2 - kt * 20;
    const int k0 = kt * 32, f0 = ft * 32;
#pragma unroll
    for (int j = 0; j < 4; ++j) {
      const int kk = k0 + ty + j * 8;
      T[ty + j * 8][tx] = (kk < 512) ? W_enc[kk * 640 + f0 + tx]
                                     : W_ot[(kk - 512) * 640 + f0 + tx];
    }
    __syncthreads();
#pragma unroll
    for (int j = 0; j < 4; ++j) {
      const int ff = f0 + ty + j * 8;
      WcatT[ff * 1024 + k0 + tx] = (bf16_t)T[tx][ty + j * 8];
    }
    return;
  }
  if (b < 1860) {  // WdecT [f][k] <- [k][f]
    const int b2 = b - 1540;
    const int kt = b2 / 20, ft = b2 - kt * 20;
    const int k0 = kt * 32, f0 = ft * 32;
#pragma unroll
    for (int j = 0; j < 4; ++j)
      T[ty + j * 8][tx] = W_dec[(k0 + ty + j * 8) * 640 + f0 + tx];
    __syncthreads();
#pragma unroll
    for (int j = 0; j < 4; ++j) {
      const int ff = f0 + ty + j * 8;
      WdecT[ff * 512 + k0 + tx] = (bf16_t)T[tx][ty + j * 8];
    }
    return;
  }
  {  // WoutT8 [v][f'(perm)] i8 <- W_out [f][v]; tiles 64 f x 32 v
    const int b2 = b - 1860;  // 0..319
    const int vt = b2 / 10, ft = b2 - vt * 10;
    const int v0 = vt * 32, f0 = ft * 64;
#pragma unroll
    for (int jj = 0; jj < 8; ++jj)
      T[ty + jj * 8][tx] = W_out[(f0 + ty + jj * 8) * 1024 + v0 + tx];
    __syncthreads();
#pragma unroll
    for (int jj = 0; jj < 4; ++jj) {
      const int vloc = ty + jj * 8;
#pragma unroll
      for (int h = 0; h < 2; ++h) {
        const int floc = tx + h * 32;
        const int fperm = (floc & 3) | (((floc >> 4) & 3) << 2) |
                          (((floc >> 2) & 3) << 4);
        float w = T[floc][vloc] * (127.0f / SW_SCALE);
        w = fminf(fmaxf(w, -127.0f), 127.0f);
        WoutT8[(size_t)(v0 + vloc) * 640 + f0 + fperm] =
            (signed char)__float2int_rn(w);
      }
    }
  }
}

// ---------------------------------------------------------------------------
// Stage 1 (R13): BARRIER-FREE 64x64 tanh-GEMM. All staging wave-private
// (each wave gloads its own A/B rows into private LDS), so per-wave counted
// vmcnt is sufficient -- no __syncthreads in the K-loop at all.
// ---------------------------------------------------------------------------
__global__ __launch_bounds__(256) void gemm_tanh_kernel(
    const bf16_t* __restrict__ A, const bf16_t* __restrict__ Bt,
    const float* __restrict__ bias1, const float* __restrict__ bias2,
    float* __restrict__ out, int M, int K) {
  __shared__ __align__(16) unsigned char L[2][16384];  // [buf][wave*4K]
  const int tid = threadIdx.x;
  const int wid = tid >> 6, l = tid & 63;
  const int wm = wid >> 1, wn = wid & 1;
  const int r0 = blockIdx.y * 64, n0 = blockIdx.x * 64;

  // wave-private staging sources (source col pre-permuted for LDS swizzle)
  const int sperm = ((l & 3) ^ ((l >> 3) & 3)) * 8;  // elements
  int ra0 = r0 + wm * 32 + (l >> 2);
  if (ra0 > M - 1) ra0 = M - 1;
  int ra1 = r0 + wm * 32 + 16 + (l >> 2);
  if (ra1 > M - 1) ra1 = M - 1;
  const bf16_t* gA0 = A + (size_t)ra0 * K + sperm;
  const bf16_t* gA1 = A + (size_t)ra1 * K + sperm;
  const bf16_t* gB0 = Bt + (size_t)(n0 + wn * 32 + (l >> 2)) * K + sperm;
  const bf16_t* gB1 = gB0 + (size_t)16 * K;
  const int wb = wid * 4096;  // private region; dests wb+{0,1024,2048,3072}

  // frag read offsets (row stride 64 B, swizzled 16-B slot; 2-way max alias)
  const int lr = l & 15, kg = l >> 4;
  const int swz = (kg ^ ((lr >> 1) & 3)) << 4;
  const int aO = wb + lr * 64 + swz;         // + a*1024
  const int bO = wb + 2048 + lr * 64 + swz;  // + b*1024

#define ST1_STAGE(t, buf)                                                      \
  {                                                                            \
    GLOAD_LDS16(gA0 + (t) * 32, L[buf] + wb);                                  \
    GLOAD_LDS16(gA1 + (t) * 32, L[buf] + wb + 1024);                           \
    GLOAD_LDS16(gB0 + (t) * 32, L[buf] + wb + 2048);                           \
    GLOAD_LDS16(gB1 + (t) * 32, L[buf] + wb + 3072);                           \
  }

  f32x4 acc[2][2] = {};
  const int steps = K >> 5;
  ST1_STAGE(0, 0);
#pragma unroll 1
  for (int ks = 0; ks < steps; ++ks) {
    const int cur = ks & 1, nxt = cur ^ 1;
    if (ks < steps - 1) ST1_STAGE(ks + 1, nxt);
    __builtin_amdgcn_sched_barrier(0);
    if (ks < steps - 1) {
      asm volatile("s_waitcnt vmcnt(4)" ::: "memory");  // own t landed
    } else {
      asm volatile("s_waitcnt vmcnt(0)" ::: "memory");
    }
    __builtin_amdgcn_sched_barrier(0);
    bf16x8 af[2], bfr[2];
#pragma unroll
    for (int a = 0; a < 2; ++a)
      af[a] = *(const bf16x8*)(L[cur] + aO + a * 1024);
#pragma unroll
    for (int b = 0; b < 2; ++b)
      bfr[b] = *(const bf16x8*)(L[cur] + bO + b * 1024);
#pragma unroll
    for (int a = 0; a < 2; ++a)
#pragma unroll
      for (int b = 0; b < 2; ++b)
        acc[a][b] = __builtin_amdgcn_mfma_f32_16x16x32_bf16(af[a], bfr[b],
                                                            acc[a][b], 0, 0, 0);
  }
#undef ST1_STAGE

#pragma unroll
  for (int a = 0; a < 2; ++a)
#pragma unroll
    for (int b = 0; b < 2; ++b) {
      int col = n0 + wn * 32 + b * 16 + lr;
      float bv = bias1[col] + (bias2 ? bias2[col] : 0.0f);
#pragma unroll
      for (int j = 0; j < 4; ++j) {
        int rg = r0 + wm * 32 + a * 16 + kg * 4 + j;
        if (rg < M) out[(size_t)rg * 640 + col] = tanhf(acc[a][b][j] + bv);
      }
    }
}

// ---------------------------------------------------------------------------
// Stage 2 (R13): i8 joint GEMM, drain-free pipeline.
//  - B staging wave-private (own 64 rows -> private 4 KB LDS copy; 2x dup
//    across the wm-pair, L2-cheap) => per-wave vmcnt is CORRECT.
//  - K-loop barrier is lgkmcnt(0)+s_barrier ONLY (A ds_write visibility);
//    NO vmem drain -- next-tile B gloads + genA loads stay in flight
//    through the MFMA phase (the only real wait is post-MFMA for loads
//    issued a full phase earlier).
//  - genA loads DENSE via K-permutation (B pre-permuted in prep): phys
//    k=16c+4s+j consumed at k_lds=16s+4c+j; per-inst wave footprint is
//    fully contiguous (was 16B-used-per-64B).
// ---------------------------------------------------------------------------
__global__ __launch_bounds__(512, 4) void joint_gemm_kernel(
    const float* __restrict__ ta,            // [1600][640]
    const float* __restrict__ tb,            // [400][640]
    const signed char* __restrict__ WoutT8,  // [1024][640] i8, k-permuted
    const float* __restrict__ b_out,         // [1024]
    float* __restrict__ out) {               // [80000][1024]
  __shared__ __align__(16) signed char L[2][40960];  // A [0,8K) | B wid*4K
  const int tid = threadIdx.x;
  const int wid = tid >> 6, l = tid & 63;
  const int wm = wid >> 2, wn = wid & 3;
  const int r0 = blockIdx.y * 128;
  const int n0 = blockIdx.x * 256;

  // ---- A-gen: thread -> (row i=tid>>2, slot s=tid&3); dense phys loads ----
  const int i = tid >> 2, s = tid & 3;
  const int r = r0 + i;
  const int frow = r / 50;
  const int bidx = r / 10000;
  const int u = r - frow * 50;
  const float* taP = ta + (size_t)frow * 640 + s * 4;   // phys k = t*64+c*16+s*4
  const float* tbP = tb + (size_t)(bidx * 50 + u) * 640 + s * 4;
  const int aw = i * 64 + ((s ^ ((i >> 1) & 3)) << 4);  // swizzled ds_write

  // ---- B staging: wave-private own 64 rows (wn*64..+64), 4 insts ----
  const int sperm = ((l & 3) ^ ((l >> 3) & 3)) << 4;
  const signed char* gB =
      WoutT8 + (size_t)(n0 + wn * 64 + (l >> 2)) * 640 + sperm;
  const int dB = 8192 + wid * 4096;  // private copy base

  // ---- frag read offsets (uniform f-stride 1024 B) ----
  const int kg = l >> 4, lr15 = l & 15;
  const int swz = (kg ^ ((lr15 >> 1) & 3)) << 4;
  const int A0 = wm * 4096 + lr15 * 64 + swz;  // + f*1024
  const int B0 = dB + lr15 * 64 + swz;         // + f*1024

  f32x4 xa[4], xb[4];
  auto loadA = [&](int t) {
#pragma unroll
    for (int c = 0; c < 4; ++c) {
      xa[c] = *(const f32x4*)(taP + t * 64 + c * 16);
      xb[c] = *(const f32x4*)(tbP + t * 64 + c * 16);
    }
  };
  auto packA = [&](signed char* dst) {
    i32x4 pk;
#pragma unroll
    for (int c = 0; c < 4; ++c) {
      int q[4];
#pragma unroll
      for (int e = 0; e < 4; ++e) {
        float d = fmaxf(1.0f + xa[c][e] * xb[c][e], 1e-6f);
        float tt = (xa[c][e] + xb[c][e]) * __builtin_amdgcn_rcpf(d);
        q[e] = __float2int_rn(tt * 127.0f);
      }
      pk[c] = (q[0] & 255) | ((q[1] & 255) << 8) | ((q[2] & 255) << 16) |
              (q[3] << 24);
    }
    *(i32x4*)(dst + aw) = pk;
  };

  i32x4 acc[4][4] = {};

  // ---- prologue: stage tile 0 (serial once) ----
#pragma unroll
  for (int j = 0; j < 4; ++j)
    GLOAD_LDS16(gB + (size_t)j * 16 * 640, L[0] + dB + j * 1024);
  loadA(0);
  packA(L[0]);
  asm volatile("s_waitcnt lgkmcnt(0)" ::: "memory");
  __builtin_amdgcn_s_barrier();

#pragma unroll 1
  for (int t = 0; t < 10; ++t) {
    const int cur = t & 1, nxt = cur ^ 1;
    // 1. issue next-tile B gloads (wave-private dest)
    if (t < 9) {
      const size_t ko = (size_t)(t + 1) * 64;
#pragma unroll
      for (int j = 0; j < 4; ++j)
        GLOAD_LDS16(gB + ko + (size_t)j * 16 * 640, L[nxt] + dB + j * 1024);
    }
    __builtin_amdgcn_sched_barrier(0);
    // 2. issue next-tile dense genA loads (regs)
    if (t < 9) loadA(t + 1);
    __builtin_amdgcn_sched_barrier(0);
    // 3. counted wait: allow the 12 just-issued (4 B + 8 genA) to fly
    if (t < 9) {
      asm volatile("s_waitcnt vmcnt(12)" ::: "memory");
    } else {
      asm volatile("s_waitcnt vmcnt(0)" ::: "memory");
    }
    __builtin_amdgcn_sched_barrier(0);
    // 4. frag reads + MFMA
    i32x4 af[4];
#pragma unroll
    for (int f = 0; f < 4; ++f) af[f] = *(const i32x4*)(L[cur] + A0 + f * 1024);
#pragma unroll
    for (int bp = 0; bp < 2; ++bp) {
      i32x4 b0 = *(const i32x4*)(L[cur] + B0 + (2 * bp) * 1024);
      i32x4 b1 = *(const i32x4*)(L[cur] + B0 + (2 * bp + 1) * 1024);
#pragma unroll
      for (int a = 0; a < 4; ++a) {
        acc[a][2 * bp] = __builtin_amdgcn_mfma_i32_16x16x64_i8(
            af[a], b0, acc[a][2 * bp], 0, 0, 0);
        acc[a][2 * bp + 1] = __builtin_amdgcn_mfma_i32_16x16x64_i8(
            af[a], b1, acc[a][2 * bp + 1], 0, 0, 0);
      }
    }
    __builtin_amdgcn_sched_barrier(0);
    // 5. quantize+write A(t+1) (implicit vmcnt here waits loads issued a
    //    full phase ago -- the pipeline's single real wait)
    if (t < 9) packA(L[nxt]);
    // 6. LDS-visibility barrier only: NO vmem drain
    asm volatile("s_waitcnt lgkmcnt(0)" ::: "memory");
    __builtin_amdgcn_sched_barrier(0);
    __builtin_amdgcn_s_barrier();
    __builtin_amdgcn_sched_barrier(0);
  }

  // ---- epilogue: dequant+bias, LDS transpose, nontemporal dwordx4 ----
  __syncthreads();
  const float cfac = SW_SCALE / (127.0f * 127.0f);
  float bvl[4];
#pragma unroll
  for (int b = 0; b < 4; ++b) bvl[b] = b_out[n0 + wn * 64 + b * 16 + lr15];

  float* ep = (float*)(void*)L + (size_t)wid * (16 * 68);
  const int rowr = l >> 4;
  const int col4 = lr15 * 4;

#pragma unroll
  for (int a = 0; a < 4; ++a) {
#pragma unroll
    for (int b = 0; b < 4; ++b) {
      const i32x4 v = acc[a][b];
#pragma unroll
      for (int j = 0; j < 4; ++j)
        ep[(kg * 4 + j) * 68 + b * 16 + lr15] = (float)v[j] * cfac + bvl[b];
    }
    asm volatile("s_waitcnt lgkmcnt(0)" ::: "memory");
#pragma unroll
    for (int it = 0; it < 4; ++it) {
      const int row = it * 4 + rowr;
      f32x4 v = *(const f32x4*)(ep + row * 68 + col4);
      const int rg = r0 + wm * 64 + a * 16 + row;
      __builtin_nontemporal_store(
          v, (f32x4*)(out + (size_t)rg * 1024 + n0 + wn * 64 + col4));
    }
  }
}

// ---------------------------------------------------------------------------
extern "C" void kernel_launch(void* const* d_in, const int* in_sizes, int n_in,
                              void* d_out, int out_size, void* d_ws,
                              size_t ws_size, hipStream_t stream) {
  const float* enc = (const float*)d_in[0];
  const float* dec = (const float*)d_in[1];
  const float* ot = (const float*)d_in[2];
  const float* W_enc = (const float*)d_in[3];
  const float* b_enc = (const float*)d_in[4];
  const float* W_ot = (const float*)d_in[5];
  const float* b_ot = (const float*)d_in[6];
  const float* W_dec = (const float*)d_in[7];
  const float* b_dec = (const float*)d_in[8];
  const float* W_out = (const float*)d_in[9];
  const float* b_out = (const float*)d_in[10];
  float* out = (float*)d_out;

  char* ws = (char*)d_ws;
  size_t off = 0;
  auto alloc = [&](size_t bytes) {
    void* p = ws + off;
    off += (bytes + 255) & ~(size_t)255;
    return p;
  };
  float* ta = (float*)alloc(1600 * 640 * 4);
  float* tb = (float*)alloc(400 * 640 * 4);
  bf16_t* Acat = (bf16_t*)alloc(1600 * 1024 * 2);
  bf16_t* Dec = (bf16_t*)alloc(400 * 512 * 2);
  bf16_t* WcatT = (bf16_t*)alloc(640 * 1024 * 2);
  bf16_t* WdecT = (bf16_t*)alloc(640 * 512 * 2);
  signed char* WoutT8 = (signed char*)alloc(1024 * 640);

  // prep: 900 elementwise + 640 WcatT + 320 WdecT + 320 WoutT8 tiles
  prep_kernel<<<2180, 256, 0, stream>>>(enc, dec, ot, W_enc, W_ot, W_dec,
                                        W_out, Acat, Dec, WcatT, WdecT, WoutT8);
  gemm_tanh_kernel<<<dim3(10, 25), 256, 0, stream>>>(Acat, WcatT, b_enc, b_ot,
                                                     ta, 1600, 1024);
  gemm_tanh_kernel<<<dim3(10, 7), 256, 0, stream>>>(Dec, WdecT, b_dec, nullptr,
                                                    tb, 400, 512);
  // joint: drain-free pipeline, wave-private B, dense genA
  joint_gemm_kernel<<<dim3(4, 625), 512, 0, stream>>>(ta, tb, WoutT8, b_out,
                                                      out);
}